// Round 3
// baseline (976.717 us; speedup 1.0000x reference)
//
#include <hip/hip_runtime.h>
#include <hip/hip_bf16.h>
#include <math.h>

#define NB 16
#define TT 800
#define FF 90
#define SS 128
#define LL 200
#define NEGV (-1e30f)

#define VSTR 68    // Vbuf row stride in 32-bit words (64 used + pad, 16B aligned)
#define PSTR 104   // prow row stride in floats

typedef __attribute__((ext_vector_type(8))) short short8;
typedef __attribute__((ext_vector_type(4))) float float4v;

static __device__ __forceinline__ unsigned short f2bf(float x) {
    union { float f; unsigned u; } v; v.f = x;
    unsigned r = (v.u + 0x7FFFu + ((v.u >> 16) & 1u)) >> 16;
    return (unsigned short)r;
}

// block 0: denominator, all 16 utts batched via MFMA (4 waves, 1 barrier/step)
// blocks 1..4: numerator, one wave per utt, barrier-free
__global__ __launch_bounds__(256) void mmi_forward(
    const float* __restrict__ x,          // N*T*F log-softmax
    const int*   __restrict__ sup,        // N*3
    const float* __restrict__ trans,      // S*S
    const int*   __restrict__ den_labels, // S
    const int*   __restrict__ num_labels, // N*L
    const int*   __restrict__ num_lens,   // N
    float*       __restrict__ ws)
{
    __shared__ __align__(16) unsigned Vbuf[2][NB * VSTR]; // bf16-pair packed V
    __shared__ __align__(16) float prow[2][NB * PSTR];    // exp(x_t) rows
    __shared__ __align__(16) float sred[NB];              // per-utt scale proxy
    __shared__ __align__(16) float wsum[NB * 4];          // [u][w] final partials
    __shared__ float lgm[NB];

    const int tid = threadIdx.x;

    if (blockIdx.x == 0) {
        // ================= denominator =================
        const int l = tid & 63, w = tid >> 6;
        const int m15 = l & 15, q = l >> 4;

        int nf4[4];
        #pragma unroll
        for (int r = 0; r < 4; ++r) nf4[r] = sup[(q * 4 + r) * 3 + 2];
        int nfmax = 0;
        for (int u = 0; u < NB; ++u) nfmax = max(nfmax, sup[u * 3 + 2]);

        // B fragments: B[k=(l>>4)*8+j][n=l&15], E = exp(trans)
        short8 bfrag[2][4];
        int lab2[2];
        #pragma unroll
        for (int n1 = 0; n1 < 2; ++n1) {
            const int ng = w * 32 + n1 * 16 + m15;
            lab2[n1] = den_labels[ng];
            #pragma unroll
            for (int c = 0; c < 4; ++c) {
                short8 f;
                #pragma unroll
                for (int j = 0; j < 8; ++j) {
                    const int k = c * 32 + q * 8 + j;
                    f[j] = (short)f2bf(__expf(trans[k * SS + ng]));
                }
                bfrag[n1][c] = f;
            }
        }

        // init V(0): v[u][0]=1 else 0 (bf16(1.0)=0x3F80 in low half of word 0)
        for (int i = tid; i < NB * VSTR; i += 256)
            Vbuf[0][i] = ((i % VSTR) == 0) ? 0x00003F80u : 0u;

        // emission rows: prow[0] = exp(row 0); pr = raw row 1
        float pr[6];
        {
            const int up = tid >> 4;
            const float* xr0 = x + (size_t)up * TT * FF;
            #pragma unroll
            for (int r = 0; r < 6; ++r) {
                const int f = (tid & 15) + 16 * r;
                if (f < FF) prow[0][up * PSTR + f] = __expf(xr0[f]);
            }
            const float* xr1 = xr0 + FF;
            #pragma unroll
            for (int r = 0; r < 6; ++r) {
                const int f = (tid & 15) + 16 * r;
                pr[r] = (f < FF) ? xr1[f] : 0.0f;
            }
        }

        float vprev[2][4];
        #pragma unroll
        for (int n1 = 0; n1 < 2; ++n1)
            #pragma unroll
            for (int r = 0; r < 4; ++r)
                vprev[n1][r] = (w == 0 && n1 == 0 && m15 == 0) ? 1.0f : 0.0f;
        int eacc[4] = {0, 0, 0, 0};   // accumulated power-of-2 shifts

        for (int t = 0; t < nfmax; ++t) {
            __syncthreads();   // V(t), prow(t), sred(t-1) all visible

            // A fragments: A[m=l&15][k=q*8+j] per 32-wide K chunk
            const unsigned* vb = Vbuf[t & 1];
            short8 afrag[4];
            #pragma unroll
            for (int c = 0; c < 4; ++c)
                afrag[c] = *(const short8*)(vb + m15 * VSTR + c * 16 + q * 4);

            // stage exp(row t+1) into prow[(t+1)&1]; prefetch raw row t+2
            {
                float* pw = prow[(t + 1) & 1];
                const int up = tid >> 4;
                #pragma unroll
                for (int r = 0; r < 6; ++r) {
                    const int f = (tid & 15) + 16 * r;
                    if (f < FF) pw[up * PSTR + f] = __expf(pr[r]);
                }
                const int t2 = min(t + 2, TT - 1);
                const float* xr = x + ((size_t)up * TT + t2) * FF;
                #pragma unroll
                for (int r = 0; r < 6; ++r) {
                    const int f = (tid & 15) + 16 * r;
                    pr[r] = (f < FF) ? xr[f] : 0.0f;
                }
            }

            // MFMA: acc[n1][r] = sum_k V[utt=4q+r][k] * E[k][dest]
            float4v acc[2];
            #pragma unroll
            for (int n1 = 0; n1 < 2; ++n1) {
                float4v c4 = {0.f, 0.f, 0.f, 0.f};
                #pragma unroll
                for (int c = 0; c < 4; ++c)
                    c4 = __builtin_amdgcn_mfma_f32_16x16x32_bf16(
                        afrag[c], bfrag[n1][c], c4, 0, 0, 0);
                acc[n1] = c4;
            }

            // delayed exact power-of-2 renorm from state-0 proxy
            float inv4[4] = {1.f, 1.f, 1.f, 1.f};
            if (t > 0) {
                const float4v m4 = *(const float4v*)(sred + 4 * q);
                #pragma unroll
                for (int r = 0; r < 4; ++r) {
                    const unsigned mb = __float_as_uint(m4[r]);
                    const int e = (int)((mb >> 23) & 255u);
                    inv4[r] = __uint_as_float((unsigned)(254 - e) << 23);
                    if (t < nf4[r]) eacc[r] += (e - 127);
                }
            }

            // emission apply + freeze select
            const float* pg = prow[t & 1];
            float vnew[2][4];
            #pragma unroll
            for (int n1 = 0; n1 < 2; ++n1) {
                #pragma unroll
                for (int r = 0; r < 4; ++r) {
                    const float p = pg[(q * 4 + r) * PSTR + lab2[n1]];
                    const float val = acc[n1][r] * p * inv4[r];
                    vnew[n1][r] = (t < nf4[r]) ? val : vprev[n1][r];
                }
            }

            // scale proxy: post-scale value at dest 0 (wave 0, m15==0)
            if (w == 0 && m15 == 0) {
                float4v t4 = {vnew[0][0], vnew[0][1], vnew[0][2], vnew[0][3]};
                *(float4v*)(sred + 4 * q) = t4;
            }

            // pack pairs to bf16 and write V(t+1)
            unsigned* vw = Vbuf[(t + 1) & 1];
            #pragma unroll
            for (int n1 = 0; n1 < 2; ++n1) {
                #pragma unroll
                for (int r = 0; r < 4; ++r) {
                    const float nb = __shfl_xor(vnew[n1][r], 1, 64);
                    if (!(m15 & 1)) {
                        const unsigned pk =
                            (unsigned)f2bf(vnew[n1][r]) | ((unsigned)f2bf(nb) << 16);
                        vw[(q * 4 + r) * VSTR + w * 16 + n1 * 8 + (m15 >> 1)] = pk;
                    }
                    vprev[n1][r] = vnew[n1][r];
                }
            }
        }

        // final: score[u] = eacc*ln2 + log(sum_d v[u][d])
        #pragma unroll
        for (int r = 0; r < 4; ++r) {
            float s = vprev[0][r] + vprev[1][r];
            #pragma unroll
            for (int off = 1; off < 16; off <<= 1)
                s += __shfl_xor(s, off, 64);
            if (m15 == 0) wsum[(q * 4 + r) * 4 + w] = s;
        }
        if (w == 0 && m15 == 0) {
            #pragma unroll
            for (int r = 0; r < 4; ++r)
                lgm[q * 4 + r] = (float)eacc[r] * 0.69314718055994531f;
        }
        __syncthreads();
        if (tid < NB) {
            const float s = wsum[tid * 4 + 0] + wsum[tid * 4 + 1] +
                            wsum[tid * 4 + 2] + wsum[tid * 4 + 3];
            ws[tid] = lgm[tid] + __logf(s);
        }
    } else {
        // ================= numerator: one wave per utt, no barriers =============
        const int w = tid >> 6, l = tid & 63;
        const int n = (blockIdx.x - 1) * 4 + w;
        const int nf = sup[n * 3 + 2];
        const float* xb = x + (size_t)n * TT * FF;
        const int* nl = num_labels + n * LL;

        int li[4];
        #pragma unroll
        for (int k = 0; k < 4; ++k) li[k] = nl[min(4 * l + k, LL - 1)];

        float a4[4] = {NEGV, NEGV, NEGV, NEGV};  // states 4l+1..4l+4
        float ea[4], eb[4];
        #pragma unroll
        for (int k = 0; k < 4; ++k) ea[k] = xb[li[k]];
        {
            const float* xr = xb + (size_t)min(1, nf - 1) * FF;
            #pragma unroll
            for (int k = 0; k < 4; ++k) eb[k] = xr[li[k]];
        }

        auto step = [&](float (&e)[4], int t) {
            float left = __shfl_up(a4[3], 1, 64);
            if (l == 0) left = (t == 0) ? 0.0f : NEGV;
            float prev = left;
            #pragma unroll
            for (int k = 0; k < 4; ++k) {
                const float a = a4[k], b = prev;
                const float mx = fmaxf(a, b), mn = fminf(a, b);
                const float nv = mx + __logf(1.0f + __expf(mn - mx)) + e[k];
                prev = a4[k];
                a4[k] = nv;
            }
            const int t2 = min(t + 2, nf - 1);
            const float* xr = xb + (size_t)t2 * FF;
            #pragma unroll
            for (int k = 0; k < 4; ++k) e[k] = xr[li[k]];
        };

        int t = 0;
        while (t < nf) {
            step(ea, t); ++t;
            if (t >= nf) break;
            step(eb, t); ++t;
        }

        const int idx = num_lens[n] - 1;   // alpha position num_lens, state idx+1
        if ((idx >> 2) == l) {
            const int kk = idx & 3;
            float v = (kk == 0) ? a4[0] : (kk == 1) ? a4[1] : (kk == 2) ? a4[2] : a4[3];
            ws[NB + n] = v;
        }
    }
}

__global__ void mmi_finalize(const float* __restrict__ ws,
                             const int* __restrict__ sup,
                             float* __restrict__ out)
{
    const int tid = threadIdx.x;  // 64 threads
    float tot_score = 0.0f, tot_frames = 0.0f, all_frames = 0.0f;
    if (tid < NB) {
        const float tot = ws[NB + tid] - ws[tid];   // num - den (DEN_SCALE=1)
        const int nf = sup[tid * 3 + 2];
        const bool fin = isfinite(tot) && (tot > 0.5f * NEGV);
        tot_score  = fin ? tot : 0.0f;
        tot_frames = fin ? (float)nf : 0.0f;
        all_frames = (float)nf;
    }
    #pragma unroll
    for (int off = 32; off >= 1; off >>= 1) {
        tot_score  += __shfl_xor(tot_score, off, 64);
        tot_frames += __shfl_xor(tot_frames, off, 64);
        all_frames += __shfl_xor(all_frames, off, 64);
    }
    if (tid == 0) {
        out[0] = tot_score;
        out[1] = tot_frames;
        out[2] = all_frames;
    }
}

extern "C" void kernel_launch(void* const* d_in, const int* in_sizes, int n_in,
                              void* d_out, int out_size, void* d_ws, size_t ws_size,
                              hipStream_t stream) {
    const float* x          = (const float*)d_in[0];
    const int*   sup        = (const int*)d_in[1];
    const float* trans      = (const float*)d_in[2];
    const int*   den_labels = (const int*)d_in[3];
    const int*   num_labels = (const int*)d_in[4];
    const int*   num_lens   = (const int*)d_in[5];
    float* ws  = (float*)d_ws;
    float* out = (float*)d_out;

    mmi_forward<<<dim3(5), dim3(256), 0, stream>>>(
        x, sup, trans, den_labels, num_labels, num_lens, ws);
    mmi_finalize<<<dim3(1), dim3(64), 0, stream>>>(ws, sup, out);
}

// Round 4
// 375.716 us; speedup vs baseline: 2.5996x; 2.5996x over previous
//
#include <hip/hip_runtime.h>
#include <math.h>

#define NB 16
#define TT 800
#define FF 90
#define SS 128
#define LL 200
#define NEGV (-1e30f)
#define XB (16 * FF)   // 1440 floats per emission batch

// blocks 0..15: denominator FSA (linear-domain scaled GEMV, renorm every 16 steps,
//               emissions batch-staged through double-buffered LDS)
// blocks 16..19: numerator chain, one wave per utterance, barrier-free
__global__ __launch_bounds__(256) void mmi_forward(
    const float* __restrict__ x,          // N*T*F log-softmax
    const int*   __restrict__ sup,        // N*3
    const float* __restrict__ trans,      // S*S
    const int*   __restrict__ den_labels, // S
    const int*   __restrict__ num_labels, // N*L
    const int*   __restrict__ num_lens,   // N
    float*       __restrict__ ws)
{
    const int tid = threadIdx.x;

    if (blockIdx.x < NB) {
        // ---------------- denominator ----------------
        __shared__ float sh_v[SS];              // scaled linear alphas
        __shared__ float sh_part[8 * SS];       // chunk partials
        __shared__ float sh_red[4];
        __shared__ __align__(16) float xbuf[2][XB];  // raw x rows, 16-frame batches

        const int n  = blockIdx.x;
        const int nf = sup[n * 3 + 2];
        const int g  = tid & 31;   // dest group: dests 4g..4g+3
        const int c  = tid >> 5;   // source chunk: srcs 16c..16c+15

        // E fragment in registers: E[16c+j][4g+dd], 64 floats/thread
        float4 e[16];
        #pragma unroll
        for (int j = 0; j < 16; ++j) {
            const float4 t4 = *(const float4*)(trans + (size_t)(16 * c + j) * SS + 4 * g);
            e[j] = make_float4(__expf(t4.x), __expf(t4.y), __expf(t4.z), __expf(t4.w));
        }

        const int lab = (tid < SS) ? den_labels[tid & (SS - 1)] : 0;
        const float* xb = x + (size_t)n * TT * FF;

        // stage batch 0 into xbuf[0] (one-time drain before loop)
        {
            const float4* s0 = (const float4*)xb;
            float4 p0 = s0[tid];
            float4 p1; if (tid < 104) p1 = s0[256 + tid];
            float4* d0 = (float4*)xbuf[0];
            d0[tid] = p0;
            if (tid < 104) d0[256 + tid] = p1;
        }
        if (tid < SS) sh_v[tid] = (tid == 0) ? 1.0f : 0.0f;
        float logM = 0.0f, v = 0.0f, pe = 0.0f;
        float4 pf0, pf1;   // next-batch prefetch registers
        __syncthreads();

        for (int t = 0; t < nf; ++t) {
            const int b = t >> 4;
            // ---- phase A: emission from LDS batch; GEMV partials ----
            if (tid < SS)
                pe = __expf(xbuf[b & 1][(t & 15) * FF + lab]);

            float4 aa[4];
            {
                const float4* av = (const float4*)(sh_v + 16 * c);
                aa[0] = av[0]; aa[1] = av[1]; aa[2] = av[2]; aa[3] = av[3];
            }
            const float* as = (const float*)aa;
            float4 acc = make_float4(0.f, 0.f, 0.f, 0.f);
            #pragma unroll
            for (int j = 0; j < 16; ++j) {
                acc.x = fmaf(as[j], e[j].x, acc.x);
                acc.y = fmaf(as[j], e[j].y, acc.y);
                acc.z = fmaf(as[j], e[j].z, acc.z);
                acc.w = fmaf(as[j], e[j].w, acc.w);
            }
            *(float4*)(sh_part + c * SS + 4 * g) = acc;

            // issue next-batch global prefetch mid-batch (7 steps of slack)
            if ((t & 15) == 8) {
                const int tn = (b + 1) * 16;
                if (tn < nf) {
                    const float4* s = (const float4*)(xb + (size_t)tn * FF);
                    pf0 = s[tid];
                    if (tid < 104) pf1 = s[256 + tid];
                }
            }
            __syncthreads();   // partials ready (lgkm-only drain most steps)

            // ---- phase B: reduce 8 chunks, apply emission, periodic renorm ----
            const bool rs = ((t & 15) == 15);
            if (tid < SS) {
                float y = 0.0f;
                #pragma unroll
                for (int cc = 0; cc < 8; ++cc) y += sh_part[cc * SS + tid];
                v = y * pe;
                if (rs) {
                    float m = v;
                    #pragma unroll
                    for (int off = 32; off >= 1; off >>= 1)
                        m = fmaxf(m, __shfl_xor(m, off, 64));
                    if ((tid & 63) == 0) sh_red[tid >> 6] = m;
                }
            }
            // commit prefetched batch b+1 into the other LDS buffer
            if (rs) {
                const int tn = (b + 1) * 16;
                if (tn < nf) {
                    float4* d = (float4*)xbuf[(b + 1) & 1];
                    d[tid] = pf0;
                    if (tid < 104) d[256 + tid] = pf1;
                }
                __syncthreads();
                if (tid < SS) {
                    float mm = fmaxf(sh_red[0], sh_red[1]);
                    mm = fmaxf(mm, 1e-37f);
                    v *= (1.0f / mm);
                    logM += __logf(mm);
                }
            }
            if (tid < SS) sh_v[tid] = v;
            __syncthreads();   // alphas (and new batch) visible for next step
        }

        // den score = logM + log(sum_s v[s])
        if (tid < SS) {
            float ssum = v;
            #pragma unroll
            for (int off = 32; off >= 1; off >>= 1)
                ssum += __shfl_xor(ssum, off, 64);
            if ((tid & 63) == 0) sh_red[2 + (tid >> 6)] = ssum;
        }
        __syncthreads();
        if (tid == 0) ws[n] = logM + __logf(sh_red[2] + sh_red[3]);
    } else {
        // ------------- numerator: one wave per utt, no barriers -------------
        const int w = tid >> 6, l = tid & 63;
        const int n = (blockIdx.x - NB) * 4 + w;
        const int nf = sup[n * 3 + 2];
        const float* xb = x + (size_t)n * TT * FF;
        const int* nl = num_labels + n * LL;

        int li[4];
        #pragma unroll
        for (int k = 0; k < 4; ++k) li[k] = nl[min(4 * l + k, LL - 1)];

        float a4[4] = {NEGV, NEGV, NEGV, NEGV};  // states 4l+1..4l+4
        float ea[4], eb[4];
        #pragma unroll
        for (int k = 0; k < 4; ++k) ea[k] = xb[li[k]];
        {
            const float* xr = xb + (size_t)min(1, nf - 1) * FF;
            #pragma unroll
            for (int k = 0; k < 4; ++k) eb[k] = xr[li[k]];
        }

        auto step = [&](float (&ee)[4], int t) {
            float left = __shfl_up(a4[3], 1, 64);
            if (l == 0) left = (t == 0) ? 0.0f : NEGV;
            float prev = left;
            #pragma unroll
            for (int k = 0; k < 4; ++k) {
                const float a = a4[k], b = prev;
                const float mx = fmaxf(a, b), mn = fminf(a, b);
                const float nv = mx + __logf(1.0f + __expf(mn - mx)) + ee[k];
                prev = a4[k];
                a4[k] = nv;
            }
            const int t2 = min(t + 2, nf - 1);
            const float* xr = xb + (size_t)t2 * FF;
            #pragma unroll
            for (int k = 0; k < 4; ++k) ee[k] = xr[li[k]];
        };

        int t = 0;
        while (t < nf) {
            step(ea, t); ++t;
            if (t >= nf) break;
            step(eb, t); ++t;
        }

        const int idx = num_lens[n] - 1;   // alpha position num_lens = state idx+1
        if ((idx >> 2) == l) {
            const int kk = idx & 3;
            float vv = (kk == 0) ? a4[0] : (kk == 1) ? a4[1] : (kk == 2) ? a4[2] : a4[3];
            ws[NB + n] = vv;
        }
    }
}

__global__ void mmi_finalize(const float* __restrict__ ws,
                             const int* __restrict__ sup,
                             float* __restrict__ out)
{
    const int tid = threadIdx.x;  // 64 threads
    float tot_score = 0.0f, tot_frames = 0.0f, all_frames = 0.0f;
    if (tid < NB) {
        const float tot = ws[NB + tid] - ws[tid];   // num - den (DEN_SCALE=1)
        const int nf = sup[tid * 3 + 2];
        const bool fin = isfinite(tot) && (tot > 0.5f * NEGV);
        tot_score  = fin ? tot : 0.0f;
        tot_frames = fin ? (float)nf : 0.0f;
        all_frames = (float)nf;
    }
    #pragma unroll
    for (int off = 32; off >= 1; off >>= 1) {
        tot_score  += __shfl_xor(tot_score, off, 64);
        tot_frames += __shfl_xor(tot_frames, off, 64);
        all_frames += __shfl_xor(all_frames, off, 64);
    }
    if (tid == 0) {
        out[0] = tot_score;
        out[1] = tot_frames;
        out[2] = all_frames;
    }
}

extern "C" void kernel_launch(void* const* d_in, const int* in_sizes, int n_in,
                              void* d_out, int out_size, void* d_ws, size_t ws_size,
                              hipStream_t stream) {
    const float* x          = (const float*)d_in[0];
    const int*   sup        = (const int*)d_in[1];
    const float* trans      = (const float*)d_in[2];
    const int*   den_labels = (const int*)d_in[3];
    const int*   num_labels = (const int*)d_in[4];
    const int*   num_lens   = (const int*)d_in[5];
    float* ws  = (float*)d_ws;
    float* out = (float*)d_out;

    mmi_forward<<<dim3(20), dim3(256), 0, stream>>>(
        x, sup, trans, den_labels, num_labels, num_lens, ws);
    mmi_finalize<<<dim3(1), dim3(64), 0, stream>>>(ws, sup, out);
}